// Round 1
// baseline (447.654 us; speedup 1.0000x reference)
//
#include <hip/hip_runtime.h>

#define NN 50000
#define NE 800000
#define DD 128
#define ED 32

__device__ __forceinline__ float4 ld4(const float* p) {
    return *reinterpret_cast<const float4*>(p);
}
__device__ __forceinline__ void fma4(float4& a, float s, float4 w) {
    a.x = fmaf(s, w.x, a.x);
    a.y = fmaf(s, w.y, a.y);
    a.z = fmaf(s, w.z, a.z);
    a.w = fmaf(s, w.w, a.w);
}

// ---------------------------------------------------------------- edge stage
// one wave per edge; We columns (lane, lane+64) in registers; edge row via
// scalar loads (wave-uniform); scatter via native f32 atomics.
__global__ __launch_bounds__(256, 4)
void k_edge(const float* __restrict__ x, const int* __restrict__ ei,
            const float* __restrict__ ea, const float* __restrict__ We,
            const float* __restrict__ be, float* __restrict__ agg)
{
    const int lane = threadIdx.x & 63;
    const int wid  = (blockIdx.x << 2) | (threadIdx.x >> 6);
    const int nw   = gridDim.x << 2;

    float w0[ED], w1[ED];
#pragma unroll
    for (int k = 0; k < ED; ++k) {
        w0[k] = We[k * DD + lane];
        w1[k] = We[k * DD + 64 + lane];
    }
    const float b0 = be[lane], b1 = be[64 + lane];

    // int64-vs-int32 sniff: int64 indices < 2^32 have zero high words.
    const int is64 = ((ei[1] | ei[3] | ei[5] | ei[7]) == 0) ? 1 : 0;

    const int chunk = (NE + nw - 1) / nw;
    const int eBeg = wid * chunk;
    const int eEnd = min(eBeg + chunk, NE);
    for (int e = eBeg; e < eEnd; ++e) {
        const int es  = __builtin_amdgcn_readfirstlane(e);
        const int src = ei[es << is64];
        const int dst = ei[(NE + es) << is64];
        const float* eap = ea + (size_t)es * ED;
        float a0 = b0, a1 = b1;
#pragma unroll
        for (int k = 0; k < ED; ++k) {
            const float v = eap[k];       // wave-uniform -> scalar load
            a0 = fmaf(v, w0[k], a0);
            a1 = fmaf(v, w1[k], a1);
        }
        const float* xr = x + (size_t)src * DD;
        const float m0 = fmaxf(xr[lane] + a0, 0.0f);
        const float m1 = fmaxf(xr[lane + 64] + a1, 0.0f);
        float* ar = agg + (size_t)dst * DD;
        unsafeAtomicAdd(ar + lane, m0);
        unsafeAtomicAdd(ar + lane + 64, m1);
    }
}

// ---------------------------------------------------------------- conv stage
// conv = (x + agg) @ Wc + bc.  Wc in LDS (64KB).  Half-wave computes 4 nodes,
// each lane owns a d-quad (d = 4q..4q+3, q = lane&31).
__global__ __launch_bounds__(256, 2)
void k_conv(const float* __restrict__ x, const float* __restrict__ agg,
            const float* __restrict__ Wc, const float* __restrict__ bc,
            float* __restrict__ conv)
{
    __shared__ float sW[DD * DD];
    for (int i = threadIdx.x * 4; i < DD * DD; i += 1024)
        *reinterpret_cast<float4*>(&sW[i]) = ld4(&Wc[i]);
    __syncthreads();

    const int lane = threadIdx.x & 63;
    const int q    = lane & 31;
    const int wib  = threadIdx.x >> 6;
    const int half = lane >> 5;

    const float4 bcv = ld4(&bc[q * 4]);
    const int ntiles = (NN + 31) / 32;

    for (int tile = blockIdx.x; tile < ntiles; tile += gridDim.x) {
        const int base = tile * 32 + wib * 8 + half * 4;
        const int n0 = min(base + 0, NN - 1);
        const int n1 = min(base + 1, NN - 1);
        const int n2 = min(base + 2, NN - 1);
        const int n3 = min(base + 3, NN - 1);
        const float* x0 = x + (size_t)n0 * DD; const float* g0 = agg + (size_t)n0 * DD;
        const float* x1 = x + (size_t)n1 * DD; const float* g1 = agg + (size_t)n1 * DD;
        const float* x2 = x + (size_t)n2 * DD; const float* g2 = agg + (size_t)n2 * DD;
        const float* x3 = x + (size_t)n3 * DD; const float* g3 = agg + (size_t)n3 * DD;
        float4 acc0 = bcv, acc1 = bcv, acc2 = bcv, acc3 = bcv;
#pragma unroll 2
        for (int j = 0; j < DD; j += 4) {
            const float4 wv0 = ld4(&sW[(j + 0) * DD + q * 4]);
            const float4 wv1 = ld4(&sW[(j + 1) * DD + q * 4]);
            const float4 wv2 = ld4(&sW[(j + 2) * DD + q * 4]);
            const float4 wv3 = ld4(&sW[(j + 3) * DD + q * 4]);
            float4 xa, ga;
            xa = ld4(x0 + j); ga = ld4(g0 + j);
            fma4(acc0, xa.x + ga.x, wv0); fma4(acc0, xa.y + ga.y, wv1);
            fma4(acc0, xa.z + ga.z, wv2); fma4(acc0, xa.w + ga.w, wv3);
            xa = ld4(x1 + j); ga = ld4(g1 + j);
            fma4(acc1, xa.x + ga.x, wv0); fma4(acc1, xa.y + ga.y, wv1);
            fma4(acc1, xa.z + ga.z, wv2); fma4(acc1, xa.w + ga.w, wv3);
            xa = ld4(x2 + j); ga = ld4(g2 + j);
            fma4(acc2, xa.x + ga.x, wv0); fma4(acc2, xa.y + ga.y, wv1);
            fma4(acc2, xa.z + ga.z, wv2); fma4(acc2, xa.w + ga.w, wv3);
            xa = ld4(x3 + j); ga = ld4(g3 + j);
            fma4(acc3, xa.x + ga.x, wv0); fma4(acc3, xa.y + ga.y, wv1);
            fma4(acc3, xa.z + ga.z, wv2); fma4(acc3, xa.w + ga.w, wv3);
        }
        if (base + 0 < NN) *reinterpret_cast<float4*>(&conv[(size_t)n0 * DD + q * 4]) = acc0;
        if (base + 1 < NN) *reinterpret_cast<float4*>(&conv[(size_t)n1 * DD + q * 4]) = acc1;
        if (base + 2 < NN) *reinterpret_cast<float4*>(&conv[(size_t)n2 * DD + q * 4]) = acc2;
        if (base + 3 < NN) *reinterpret_cast<float4*>(&conv[(size_t)n3 * DD + q * 4]) = acc3;
    }
}

// ---------------------------------------------------------------- gate stage
// gate = sigmoid(conv @ Wg[0:128] + imp*Wg[128] + bg); out = x + g*(conv-x);
// prop = out @ Wp + bp.  conv is read from d_out and overwritten in place.
__global__ __launch_bounds__(256, 2)
void k_gate(const float* __restrict__ x, const float* conv,
            const float* __restrict__ imp, const float* __restrict__ Wg,
            const float* __restrict__ bg, const float* __restrict__ Wp,
            const float* __restrict__ bp, float* outp, float* __restrict__ prop)
{
    __shared__ float sW[DD * DD];
    for (int i = threadIdx.x * 4; i < DD * DD; i += 1024)
        *reinterpret_cast<float4*>(&sW[i]) = ld4(&Wg[i]);   // rows 0..127
    __syncthreads();

    const int lane = threadIdx.x & 63;
    const int q    = lane & 31;
    const int wib  = threadIdx.x >> 6;
    const int half = lane >> 5;

    const float4 bgv = ld4(&bg[q * 4]);
    const float4 wgi = ld4(&Wg[DD * DD + q * 4]);   // importance row (row 128)
    const float4 wp4 = ld4(&Wp[q * 4]);
    const float  bps = bp[0];
    const int ntiles = (NN + 31) / 32;

    for (int tile = blockIdx.x; tile < ntiles; tile += gridDim.x) {
        const int base = tile * 32 + wib * 8 + half * 4;
        const int n0 = min(base + 0, NN - 1);
        const int n1 = min(base + 1, NN - 1);
        const int n2 = min(base + 2, NN - 1);
        const int n3 = min(base + 3, NN - 1);
        const float* c0 = conv + (size_t)n0 * DD;
        const float* c1 = conv + (size_t)n1 * DD;
        const float* c2 = conv + (size_t)n2 * DD;
        const float* c3 = conv + (size_t)n3 * DD;
        float4 acc0 = bgv, acc1 = bgv, acc2 = bgv, acc3 = bgv;
#pragma unroll 2
        for (int j = 0; j < DD; j += 4) {
            const float4 wv0 = ld4(&sW[(j + 0) * DD + q * 4]);
            const float4 wv1 = ld4(&sW[(j + 1) * DD + q * 4]);
            const float4 wv2 = ld4(&sW[(j + 2) * DD + q * 4]);
            const float4 wv3 = ld4(&sW[(j + 3) * DD + q * 4]);
            float4 cv;
            cv = ld4(c0 + j);
            fma4(acc0, cv.x, wv0); fma4(acc0, cv.y, wv1);
            fma4(acc0, cv.z, wv2); fma4(acc0, cv.w, wv3);
            cv = ld4(c1 + j);
            fma4(acc1, cv.x, wv0); fma4(acc1, cv.y, wv1);
            fma4(acc1, cv.z, wv2); fma4(acc1, cv.w, wv3);
            cv = ld4(c2 + j);
            fma4(acc2, cv.x, wv0); fma4(acc2, cv.y, wv1);
            fma4(acc2, cv.z, wv2); fma4(acc2, cv.w, wv3);
            cv = ld4(c3 + j);
            fma4(acc3, cv.x, wv0); fma4(acc3, cv.y, wv1);
            fma4(acc3, cv.z, wv2); fma4(acc3, cv.w, wv3);
        }

        float s[4];
        const int   ns[4] = {n0, n1, n2, n3};
        float4      as[4] = {acc0, acc1, acc2, acc3};
#pragma unroll
        for (int m = 0; m < 4; ++m) {
            const int n = ns[m];
            float4 a = as[m];
            fma4(a, imp[n], wgi);
            float4 g;
            g.x = 1.0f / (1.0f + expf(-a.x));
            g.y = 1.0f / (1.0f + expf(-a.y));
            g.z = 1.0f / (1.0f + expf(-a.z));
            g.w = 1.0f / (1.0f + expf(-a.w));
            const float4 cv = ld4(&conv[(size_t)n * DD + q * 4]);
            const float4 xv = ld4(&x[(size_t)n * DD + q * 4]);
            float4 o;
            o.x = fmaf(g.x, cv.x - xv.x, xv.x);
            o.y = fmaf(g.y, cv.y - xv.y, xv.y);
            o.z = fmaf(g.z, cv.z - xv.z, xv.z);
            o.w = fmaf(g.w, cv.w - xv.w, xv.w);
            if (base + m < NN)
                *reinterpret_cast<float4*>(&outp[(size_t)n * DD + q * 4]) = o;
            s[m] = o.x * wp4.x + o.y * wp4.y + o.z * wp4.z + o.w * wp4.w;
        }
#pragma unroll
        for (int off = 16; off; off >>= 1) {
            s[0] += __shfl_xor(s[0], off);
            s[1] += __shfl_xor(s[1], off);
            s[2] += __shfl_xor(s[2], off);
            s[3] += __shfl_xor(s[3], off);
        }
        if (q == 0) {
#pragma unroll
            for (int m = 0; m < 4; ++m)
                if (base + m < NN) prop[base + m] = s[m] + bps;
        }
    }
}

extern "C" void kernel_launch(void* const* d_in, const int* in_sizes, int n_in,
                              void* d_out, int out_size, void* d_ws, size_t ws_size,
                              hipStream_t stream) {
    const float* x   = (const float*)d_in[0];
    const int*   ei  = (const int*)d_in[1];
    const float* ea  = (const float*)d_in[2];
    const float* imp = (const float*)d_in[3];
    const float* We  = (const float*)d_in[4];
    const float* be  = (const float*)d_in[5];
    const float* Wc  = (const float*)d_in[6];
    const float* bc  = (const float*)d_in[7];
    const float* Wg  = (const float*)d_in[8];
    const float* bg  = (const float*)d_in[9];
    const float* Wp  = (const float*)d_in[10];
    const float* bp  = (const float*)d_in[11];

    float* out  = (float*)d_out;                 // [NN, DD]
    float* prop = out + (size_t)NN * DD;         // [NN]
    float* agg  = (float*)d_ws;                  // [NN, DD] scratch

    hipMemsetAsync(agg, 0, (size_t)NN * DD * sizeof(float), stream);
    hipLaunchKernelGGL(k_edge, dim3(4096), dim3(256), 0, stream, x, ei, ea, We, be, agg);
    hipLaunchKernelGGL(k_conv, dim3(512), dim3(256), 0, stream, x, agg, Wc, bc, out);
    hipLaunchKernelGGL(k_gate, dim3(512), dim3(256), 0, stream,
                       x, out, imp, Wg, bg, Wp, bp, out, prop);
}